// Round 1
// baseline (352.878 us; speedup 1.0000x reference)
//
#include <hip/hip_runtime.h>
#include <hip/hip_bf16.h>

#define N 8192
#define FIN 512
#define FOUT 256

typedef __attribute__((ext_vector_type(8))) short bf16x8;
typedef __attribute__((ext_vector_type(4))) float f32x4;

__device__ __forceinline__ unsigned short f2bf(float x) {
  unsigned int u = __float_as_uint(x);
  return (unsigned short)((u + 0x7FFFu + ((u >> 16) & 1u)) >> 16);
}

// ---------------------------------------------------------------------------
// K1: h = features(8192x512) @ W(512x256), fp32 vector GEMM, 64x64 tile.
// Epilogue also writes hT (bf16, [FOUT][N]) for K4's B-operand staging.
// ---------------------------------------------------------------------------
__global__ __launch_bounds__(256) void gat_k1_gemm_h(
    const float* __restrict__ A, const float* __restrict__ W,
    float* __restrict__ h, unsigned short* __restrict__ hT) {
  __shared__ __align__(16) float As[16][68];  // [k][m], pad 68 keeps f4 align + banks
  __shared__ __align__(16) float Bs[16][64];  // [k][n]
  const int tid = threadIdx.x;
  const int tx = tid & 15, ty = tid >> 4;
  const int nb = blockIdx.x * 64, mb = blockIdx.y * 64;
  float acc[4][4] = {};
  for (int k0 = 0; k0 < FIN; k0 += 16) {
#pragma unroll
    for (int i = 0; i < 4; ++i) {
      int e = tid + 256 * i;
      int m = e >> 4, k = e & 15;
      As[k][m] = A[(size_t)(mb + m) * FIN + k0 + k];
      int n2 = e & 63, k2 = e >> 6;
      Bs[k2][n2] = W[(size_t)(k0 + k2) * FOUT + nb + n2];
    }
    __syncthreads();
#pragma unroll
    for (int k = 0; k < 16; ++k) {
      float4 av = *reinterpret_cast<const float4*>(&As[k][ty * 4]);
      float4 bv = *reinterpret_cast<const float4*>(&Bs[k][tx * 4]);
      float aa[4] = {av.x, av.y, av.z, av.w};
      float bb[4] = {bv.x, bv.y, bv.z, bv.w};
#pragma unroll
      for (int i = 0; i < 4; ++i)
#pragma unroll
        for (int j = 0; j < 4; ++j) acc[i][j] = fmaf(aa[i], bb[j], acc[i][j]);
    }
    __syncthreads();
  }
#pragma unroll
  for (int i = 0; i < 4; ++i) {
    int m = mb + ty * 4 + i;
#pragma unroll
    for (int j = 0; j < 4; ++j) {
      int n = nb + tx * 4 + j;
      h[(size_t)m * FOUT + n] = acc[i][j];
      hT[(size_t)n * N + m] = f2bf(acc[i][j]);
    }
  }
}

// ---------------------------------------------------------------------------
// K2: hs[i] = h[i,:]@a[:256], hd[i] = h[i,:]@a[256:]. One wave per row.
// ---------------------------------------------------------------------------
__global__ __launch_bounds__(256) void gat_k2_hshd(
    const float* __restrict__ h, const float* __restrict__ a,
    float* __restrict__ hs, float* __restrict__ hd) {
  const int wid = threadIdx.x >> 6;
  const int lane = threadIdx.x & 63;
  const int row = blockIdx.x * 4 + wid;
  float ps = 0.f, pd = 0.f;
#pragma unroll
  for (int i = 0; i < 4; ++i) {
    int c = lane + 64 * i;
    float v = h[(size_t)row * FOUT + c];
    ps += v * a[c];
    pd += v * a[FOUT + c];
  }
#pragma unroll
  for (int off = 32; off >= 1; off >>= 1) {
    ps += __shfl_down(ps, off);
    pd += __shfl_down(pd, off);
  }
  if (lane == 0) {
    hs[row] = ps;
    hd[row] = pd;
  }
}

// ---------------------------------------------------------------------------
// K3: masked softmax rows. logit l_ij = leaky(hs_i + hd_j) if adj else -inf.
// One pass over adj per row; 32 logits/thread live in registers (static idx).
// 8 rows/block amortize the 32KB hd LDS stage. exp(-inf)=0 == ref's exp(-1e9).
// ---------------------------------------------------------------------------
__global__ __launch_bounds__(256) void gat_k3_attn(
    const float* __restrict__ adj, const float* __restrict__ hs,
    const float* __restrict__ hd, float* __restrict__ att) {
  __shared__ float hd_s[N];  // 32 KB
  __shared__ float red[4];
  const int tid = threadIdx.x;
  const int lane = tid & 63, wid = tid >> 6;
  for (int i = tid; i < N; i += 256) hd_s[i] = hd[i];
  __syncthreads();
  const int row0 = blockIdx.x * 8;
  for (int r = 0; r < 8; ++r) {
    const int row = row0 + r;
    const float hsv = hs[row];
    const float* arow = adj + (size_t)row * N;
    float l[32];
    float m = -__builtin_inff();
#pragma unroll
    for (int i = 0; i < 32; ++i) {
      int j = tid + 256 * i;
      float aj = arow[j];
      float x = hsv + hd_s[j];
      float lv = x > 0.f ? x : 0.01f * x;
      lv = (aj != 0.f) ? lv : -__builtin_inff();
      l[i] = lv;
      m = fmaxf(m, lv);
    }
#pragma unroll
    for (int off = 32; off >= 1; off >>= 1) m = fmaxf(m, __shfl_down(m, off));
    if (lane == 0) red[wid] = m;
    __syncthreads();
    m = fmaxf(fmaxf(red[0], red[1]), fmaxf(red[2], red[3]));
    __syncthreads();
    float s = 0.f;
#pragma unroll
    for (int i = 0; i < 32; ++i) {
      float e = __expf(l[i] - m);
      l[i] = e;
      s += e;
    }
#pragma unroll
    for (int off = 32; off >= 1; off >>= 1) s += __shfl_down(s, off);
    if (lane == 0) red[wid] = s;
    __syncthreads();
    s = red[0] + red[1] + red[2] + red[3];
    __syncthreads();
    const float inv = 1.f / s;
    float* orow = att + (size_t)row * N;
#pragma unroll
    for (int i = 0; i < 32; ++i) orow[tid + 256 * i] = l[i] * inv;
  }
}

// ---------------------------------------------------------------------------
// K4: output = attention @ h via bf16 MFMA 16x16x32.
// BM=BN=BK=64, 4 waves (wave tile 32x32, 2x2 fragments).
// A: att f32 -> bf16 reg-staged into XOR-swizzled LDS [row][k].
// B: hT bf16 staged with pre-swizzled source into linear LDS [n][k].
// Swizzle: 16B slot index (bits 4-6 of row byte offset) ^= (row&7).
// ---------------------------------------------------------------------------
__global__ __launch_bounds__(256) void gat_k4_out(
    const float* __restrict__ att, const unsigned short* __restrict__ hT,
    float* __restrict__ C) {
  __shared__ __align__(16) unsigned short As[64 * 64];  // 8 KB
  __shared__ __align__(16) unsigned short Bs[64 * 64];  // 8 KB
  const int tid = threadIdx.x;
  const int lane = tid & 63, wid = tid >> 6;
  const int wm = wid & 1, wn = wid >> 1;
  const int nb = blockIdx.x * 64, mb = blockIdx.y * 64;
  const int g = lane >> 4, rsel = lane & 15;
  f32x4 acc[2][2] = {};
  for (int k0 = 0; k0 < N; k0 += 64) {
    __syncthreads();
    // stage A: 64 rows x 64 k (f32->bf16), 4 float4/thread
#pragma unroll
    for (int i = 0; i < 4; ++i) {
      int e = tid + 256 * i;
      int r = e >> 4, p = e & 15;
      float4 v = *reinterpret_cast<const float4*>(
          &att[(size_t)(mb + r) * N + k0 + p * 4]);
      uint2 pk;
      pk.x = (unsigned)f2bf(v.x) | ((unsigned)f2bf(v.y) << 16);
      pk.y = (unsigned)f2bf(v.z) | ((unsigned)f2bf(v.w) << 16);
      int byte = r * 128 + ((p * 8) ^ ((r & 7) << 4));
      *reinterpret_cast<uint2*>(reinterpret_cast<char*>(As) + byte) = pk;
    }
    // stage B: 64 n x 64 k bf16, source pre-swizzled, LDS linear
#pragma unroll
    for (int i = 0; i < 2; ++i) {
      int s = tid + 256 * i;
      int n = s >> 3, kg = s & 7;
      int kgs = kg ^ (n & 7);
      uint4 v = *reinterpret_cast<const uint4*>(
          &hT[(size_t)(nb + n) * N + k0 + kgs * 8]);
      *reinterpret_cast<uint4*>(reinterpret_cast<char*>(Bs) + s * 16) = v;
    }
    __syncthreads();
#pragma unroll
    for (int ks = 0; ks < 2; ++ks) {
      bf16x8 af[2], bg[2];
#pragma unroll
      for (int f = 0; f < 2; ++f) {
        int r = wm * 32 + f * 16 + rsel;
        af[f] = *reinterpret_cast<const bf16x8*>(
            reinterpret_cast<const char*>(As) + r * 128 +
            ((ks * 64 + g * 16) ^ ((r & 7) << 4)));
        int n = wn * 32 + f * 16 + rsel;
        bg[f] = *reinterpret_cast<const bf16x8*>(
            reinterpret_cast<const char*>(Bs) + n * 128 +
            ((ks * 64 + g * 16) ^ ((n & 7) << 4)));
      }
#pragma unroll
      for (int i = 0; i < 2; ++i)
#pragma unroll
        for (int j = 0; j < 2; ++j)
          acc[i][j] =
              __builtin_amdgcn_mfma_f32_16x16x32_bf16(af[i], bg[j], acc[i][j], 0, 0, 0);
    }
  }
  // epilogue: C/D layout col=lane&15, row=(lane>>4)*4+reg
#pragma unroll
  for (int i = 0; i < 2; ++i)
#pragma unroll
    for (int j = 0; j < 2; ++j)
#pragma unroll
      for (int r = 0; r < 4; ++r) {
        int row = mb + wm * 32 + i * 16 + g * 4 + r;
        int col = nb + wn * 32 + j * 16 + rsel;
        C[(size_t)row * FOUT + col] = acc[i][j][r];
      }
}

extern "C" void kernel_launch(void* const* d_in, const int* in_sizes, int n_in,
                              void* d_out, int out_size, void* d_ws, size_t ws_size,
                              hipStream_t stream) {
  const float* features = (const float*)d_in[0];
  const float* adj = (const float*)d_in[1];
  const float* W = (const float*)d_in[2];
  const float* a = (const float*)d_in[3];

  float* out = (float*)d_out;                  // [N][FOUT]
  float* att = out + (size_t)N * FOUT;         // [N][N]

  char* ws = (char*)d_ws;
  float* h = (float*)ws;                                        // 8 MB
  unsigned short* hT = (unsigned short*)(ws + (size_t)N * FOUT * 4);  // 4 MB
  float* hs = (float*)(ws + (size_t)N * FOUT * 4 + (size_t)N * FOUT * 2);
  float* hd = hs + N;

  hipLaunchKernelGGL(gat_k1_gemm_h, dim3(FOUT / 64, N / 64), dim3(256), 0,
                     stream, features, W, h, hT);
  hipLaunchKernelGGL(gat_k2_hshd, dim3(N / 4), dim3(256), 0, stream, h, a, hs,
                     hd);
  hipLaunchKernelGGL(gat_k3_attn, dim3(N / 8), dim3(256), 0, stream, adj, hs,
                     hd, att);
  hipLaunchKernelGGL(gat_k4_out, dim3(FOUT / 64, N / 64), dim3(256), 0, stream,
                     att, hT, out);
}

// Round 2
// 272.781 us; speedup vs baseline: 1.2936x; 1.2936x over previous
//
#include <hip/hip_runtime.h>
#include <hip/hip_bf16.h>

#define N 8192
#define FIN 512
#define FOUT 256

typedef __attribute__((ext_vector_type(8))) short bf16x8;
typedef __attribute__((ext_vector_type(4))) float f32x4;

__device__ __forceinline__ unsigned short f2bf(float x) {
  unsigned int u = __float_as_uint(x);
  return (unsigned short)((u + 0x7FFFu + ((u >> 16) & 1u)) >> 16);
}

// ---------------------------------------------------------------------------
// K1: h = features(8192x512) @ W(512x256), fp32 vector GEMM, 64x64 tile.
// Epilogue also writes hT (bf16, [FOUT][N]) for K4's B-operand staging.
// ---------------------------------------------------------------------------
__global__ __launch_bounds__(256) void gat_k1_gemm_h(
    const float* __restrict__ A, const float* __restrict__ W,
    float* __restrict__ h, unsigned short* __restrict__ hT) {
  __shared__ __align__(16) float As[16][68];
  __shared__ __align__(16) float Bs[16][64];
  const int tid = threadIdx.x;
  const int tx = tid & 15, ty = tid >> 4;
  const int nb = blockIdx.x * 64, mb = blockIdx.y * 64;
  float acc[4][4] = {};
  for (int k0 = 0; k0 < FIN; k0 += 16) {
#pragma unroll
    for (int i = 0; i < 4; ++i) {
      int e = tid + 256 * i;
      int m = e >> 4, k = e & 15;
      As[k][m] = A[(size_t)(mb + m) * FIN + k0 + k];
      int n2 = e & 63, k2 = e >> 6;
      Bs[k2][n2] = W[(size_t)(k0 + k2) * FOUT + nb + n2];
    }
    __syncthreads();
#pragma unroll
    for (int k = 0; k < 16; ++k) {
      float4 av = *reinterpret_cast<const float4*>(&As[k][ty * 4]);
      float4 bv = *reinterpret_cast<const float4*>(&Bs[k][tx * 4]);
      float aa[4] = {av.x, av.y, av.z, av.w};
      float bb[4] = {bv.x, bv.y, bv.z, bv.w};
#pragma unroll
      for (int i = 0; i < 4; ++i)
#pragma unroll
        for (int j = 0; j < 4; ++j) acc[i][j] = fmaf(aa[i], bb[j], acc[i][j]);
    }
    __syncthreads();
  }
#pragma unroll
  for (int i = 0; i < 4; ++i) {
    int m = mb + ty * 4 + i;
#pragma unroll
    for (int j = 0; j < 4; ++j) {
      int n = nb + tx * 4 + j;
      h[(size_t)m * FOUT + n] = acc[i][j];
      hT[(size_t)n * N + m] = f2bf(acc[i][j]);
    }
  }
}

// ---------------------------------------------------------------------------
// K2: hs[i] = h[i,:]@a[:256], hd[i] = h[i,:]@a[256:]. One wave per row.
// ---------------------------------------------------------------------------
__global__ __launch_bounds__(256) void gat_k2_hshd(
    const float* __restrict__ h, const float* __restrict__ a,
    float* __restrict__ hs, float* __restrict__ hd) {
  const int wid = threadIdx.x >> 6;
  const int lane = threadIdx.x & 63;
  const int row = blockIdx.x * 4 + wid;
  float ps = 0.f, pd = 0.f;
#pragma unroll
  for (int i = 0; i < 4; ++i) {
    int c = lane + 64 * i;
    float v = h[(size_t)row * FOUT + c];
    ps += v * a[c];
    pd += v * a[FOUT + c];
  }
#pragma unroll
  for (int off = 32; off >= 1; off >>= 1) {
    ps += __shfl_down(ps, off);
    pd += __shfl_down(pd, off);
  }
  if (lane == 0) {
    hs[row] = ps;
    hd[row] = pd;
  }
}

// ---------------------------------------------------------------------------
// K3: masked softmax rows, float4-vectorized (G13). One streaming pass of adj
// per row; 32 logits/thread in registers (8x float4, static idx). 8 rows per
// block amortize the 32KB hd LDS stage. exp(-inf)=0 == ref's exp(-1e9).
// ---------------------------------------------------------------------------
__global__ __launch_bounds__(256) void gat_k3_attn(
    const float* __restrict__ adj, const float* __restrict__ hs,
    const float* __restrict__ hd, float* __restrict__ att) {
  __shared__ __align__(16) float hd_s[N];  // 32 KB
  __shared__ float red[4];
  const int tid = threadIdx.x;
  const int lane = tid & 63, wid = tid >> 6;
#pragma unroll
  for (int i = 0; i < 8; ++i) {
    int j = tid * 4 + 1024 * i;
    *reinterpret_cast<float4*>(&hd_s[j]) =
        *reinterpret_cast<const float4*>(&hd[j]);
  }
  __syncthreads();
  const int row0 = blockIdx.x * 8;
  for (int r = 0; r < 8; ++r) {
    const int row = row0 + r;
    const float hsv = hs[row];
    const float* arow = adj + (size_t)row * N;
    float4 l[8];
    float m = -__builtin_inff();
#pragma unroll
    for (int i = 0; i < 8; ++i) {
      int j = tid * 4 + 1024 * i;
      float4 a4 = *reinterpret_cast<const float4*>(&arow[j]);
      float4 h4 = *reinterpret_cast<const float4*>(&hd_s[j]);
      float4 lv;
      float x;
      x = hsv + h4.x; x = x > 0.f ? x : 0.01f * x;
      lv.x = (a4.x != 0.f) ? x : -__builtin_inff();
      x = hsv + h4.y; x = x > 0.f ? x : 0.01f * x;
      lv.y = (a4.y != 0.f) ? x : -__builtin_inff();
      x = hsv + h4.z; x = x > 0.f ? x : 0.01f * x;
      lv.z = (a4.z != 0.f) ? x : -__builtin_inff();
      x = hsv + h4.w; x = x > 0.f ? x : 0.01f * x;
      lv.w = (a4.w != 0.f) ? x : -__builtin_inff();
      l[i] = lv;
      m = fmaxf(m, fmaxf(fmaxf(lv.x, lv.y), fmaxf(lv.z, lv.w)));
    }
#pragma unroll
    for (int off = 32; off >= 1; off >>= 1) m = fmaxf(m, __shfl_down(m, off));
    if (lane == 0) red[wid] = m;
    __syncthreads();
    m = fmaxf(fmaxf(red[0], red[1]), fmaxf(red[2], red[3]));
    __syncthreads();
    float s = 0.f;
#pragma unroll
    for (int i = 0; i < 8; ++i) {
      float4 lv = l[i];
      lv.x = __expf(lv.x - m);
      lv.y = __expf(lv.y - m);
      lv.z = __expf(lv.z - m);
      lv.w = __expf(lv.w - m);
      l[i] = lv;
      s += lv.x + lv.y + lv.z + lv.w;
    }
#pragma unroll
    for (int off = 32; off >= 1; off >>= 1) s += __shfl_down(s, off);
    if (lane == 0) red[wid] = s;
    __syncthreads();
    s = red[0] + red[1] + red[2] + red[3];
    __syncthreads();
    const float inv = 1.f / s;
    float* orow = att + (size_t)row * N;
#pragma unroll
    for (int i = 0; i < 8; ++i) {
      float4 lv = l[i];
      lv.x *= inv; lv.y *= inv; lv.z *= inv; lv.w *= inv;
      *reinterpret_cast<float4*>(&orow[tid * 4 + 1024 * i]) = lv;
    }
  }
}

// ---------------------------------------------------------------------------
// K4: output = attention @ h via bf16 MFMA 16x16x32.
// BM=32, BN=256 (full F_out -> att read exactly once), BK=64.
// 512 threads = 8 waves, wave tile 32x32 (acc 2x2). Grid = 256 blocks (1/CU).
// Reg-staged double-buffered 1-barrier pipeline (T14 issue-early/write-late):
// tile t+1's global loads issue before tile t's compute; ds-writes after.
// A: att f32 -> bf16, XOR-swizzled LDS. B: hT bf16, pre-swizzled source.
// Swizzle: 16B-slot bits of row byte offset ^= (row&7)<<4.
// ---------------------------------------------------------------------------
__global__ __launch_bounds__(512) void gat_k4_out(
    const float* __restrict__ att, const unsigned short* __restrict__ hT,
    float* __restrict__ C) {
  __shared__ __align__(16) unsigned short As[2][32 * 64];   // 2 x 4 KB
  __shared__ __align__(16) unsigned short Bs[2][256 * 64];  // 2 x 32 KB
  const int tid = threadIdx.x;
  const int lane = tid & 63;
  const int wn = tid >> 6;  // wave id 0..7 = N-tile
  const int mb = blockIdx.x * 32;
  const int g = lane >> 4, rsel = lane & 15;
  // A-staging address (1 float4/thread): row ar (0..31), float4 slot ap (0..15)
  const int ar = tid >> 4, ap = tid & 15;
  const float* asrc = att + (size_t)(mb + ar) * N + ap * 4;
  const int abyte = ar * 128 + ((ap * 8) ^ ((ar & 7) << 4));
  // B-staging addresses (4 uint4/thread), source pre-swizzled, LDS linear
  const unsigned short* bsrc[4];
  int bbyte[4];
#pragma unroll
  for (int i = 0; i < 4; ++i) {
    int s = tid + 512 * i;
    int n = s >> 3, kg = s & 7;
    int kgs = kg ^ (n & 7);
    bsrc[i] = hT + (size_t)n * N + kgs * 8;
    bbyte[i] = s * 16;
  }

  f32x4 acc[2][2] = {};
  float4 aA;
  uint4 bB0, bB1, bB2, bB3;

  // prologue: load + write tile 0
  aA = *reinterpret_cast<const float4*>(asrc);
  bB0 = *reinterpret_cast<const uint4*>(bsrc[0]);
  bB1 = *reinterpret_cast<const uint4*>(bsrc[1]);
  bB2 = *reinterpret_cast<const uint4*>(bsrc[2]);
  bB3 = *reinterpret_cast<const uint4*>(bsrc[3]);
  {
    uint2 pk;
    pk.x = (unsigned)f2bf(aA.x) | ((unsigned)f2bf(aA.y) << 16);
    pk.y = (unsigned)f2bf(aA.z) | ((unsigned)f2bf(aA.w) << 16);
    *reinterpret_cast<uint2*>(reinterpret_cast<char*>(As[0]) + abyte) = pk;
    *reinterpret_cast<uint4*>(reinterpret_cast<char*>(Bs[0]) + bbyte[0]) = bB0;
    *reinterpret_cast<uint4*>(reinterpret_cast<char*>(Bs[0]) + bbyte[1]) = bB1;
    *reinterpret_cast<uint4*>(reinterpret_cast<char*>(Bs[0]) + bbyte[2]) = bB2;
    *reinterpret_cast<uint4*>(reinterpret_cast<char*>(Bs[0]) + bbyte[3]) = bB3;
  }

  int cur = 0;
  for (int t = 0; t < 128; ++t) {
    const int knext = (t + 1) * 64;
    if (t < 127) {  // issue next tile's loads early (latency hides under MFMA)
      aA = *reinterpret_cast<const float4*>(asrc + knext);
      bB0 = *reinterpret_cast<const uint4*>(bsrc[0] + knext);
      bB1 = *reinterpret_cast<const uint4*>(bsrc[1] + knext);
      bB2 = *reinterpret_cast<const uint4*>(bsrc[2] + knext);
      bB3 = *reinterpret_cast<const uint4*>(bsrc[3] + knext);
    }
    __syncthreads();  // buf[cur] writes from prev iter visible
    const char* Ac = reinterpret_cast<const char*>(As[cur]);
    const char* Bc = reinterpret_cast<const char*>(Bs[cur]);
#pragma unroll
    for (int ks = 0; ks < 2; ++ks) {
      bf16x8 af[2], bg[2];
#pragma unroll
      for (int f = 0; f < 2; ++f) {
        int r = f * 16 + rsel;
        af[f] = *reinterpret_cast<const bf16x8*>(
            Ac + r * 128 + ((ks * 64 + g * 16) ^ ((r & 7) << 4)));
        int n = wn * 32 + f * 16 + rsel;
        bg[f] = *reinterpret_cast<const bf16x8*>(
            Bc + n * 128 + ((ks * 64 + g * 16) ^ ((n & 7) << 4)));
      }
#pragma unroll
      for (int i = 0; i < 2; ++i)
#pragma unroll
        for (int j = 0; j < 2; ++j)
          acc[i][j] = __builtin_amdgcn_mfma_f32_16x16x32_bf16(af[i], bg[j],
                                                              acc[i][j], 0, 0, 0);
    }
    if (t < 127) {  // write prefetched regs to the other buffer
      char* An = reinterpret_cast<char*>(As[cur ^ 1]);
      char* Bn = reinterpret_cast<char*>(Bs[cur ^ 1]);
      uint2 pk;
      pk.x = (unsigned)f2bf(aA.x) | ((unsigned)f2bf(aA.y) << 16);
      pk.y = (unsigned)f2bf(aA.z) | ((unsigned)f2bf(aA.w) << 16);
      *reinterpret_cast<uint2*>(An + abyte) = pk;
      *reinterpret_cast<uint4*>(Bn + bbyte[0]) = bB0;
      *reinterpret_cast<uint4*>(Bn + bbyte[1]) = bB1;
      *reinterpret_cast<uint4*>(Bn + bbyte[2]) = bB2;
      *reinterpret_cast<uint4*>(Bn + bbyte[3]) = bB3;
      cur ^= 1;
    }
  }
  // epilogue: C/D layout col=lane&15, row=(lane>>4)*4+reg
#pragma unroll
  for (int i = 0; i < 2; ++i)
#pragma unroll
    for (int j = 0; j < 2; ++j)
#pragma unroll
      for (int r = 0; r < 4; ++r) {
        int row = mb + i * 16 + g * 4 + r;
        int col = wn * 32 + j * 16 + rsel;
        C[(size_t)row * FOUT + col] = acc[i][j][r];
      }
}

extern "C" void kernel_launch(void* const* d_in, const int* in_sizes, int n_in,
                              void* d_out, int out_size, void* d_ws, size_t ws_size,
                              hipStream_t stream) {
  const float* features = (const float*)d_in[0];
  const float* adj = (const float*)d_in[1];
  const float* W = (const float*)d_in[2];
  const float* a = (const float*)d_in[3];

  float* out = (float*)d_out;           // [N][FOUT]
  float* att = out + (size_t)N * FOUT;  // [N][N]

  char* ws = (char*)d_ws;
  float* h = (float*)ws;                                              // 8 MB
  unsigned short* hT = (unsigned short*)(ws + (size_t)N * FOUT * 4);  // 4 MB
  float* hs = (float*)(ws + (size_t)N * FOUT * 4 + (size_t)N * FOUT * 2);
  float* hd = hs + N;

  hipLaunchKernelGGL(gat_k1_gemm_h, dim3(FOUT / 64, N / 64), dim3(256), 0,
                     stream, features, W, h, hT);
  hipLaunchKernelGGL(gat_k2_hshd, dim3(N / 4), dim3(256), 0, stream, h, a, hs,
                     hd);
  hipLaunchKernelGGL(gat_k3_attn, dim3(N / 8), dim3(256), 0, stream, adj, hs,
                     hd, att);
  hipLaunchKernelGGL(gat_k4_out, dim3(N / 32), dim3(512), 0, stream, att, hT,
                     out);
}

// Round 3
// 232.440 us; speedup vs baseline: 1.5181x; 1.1736x over previous
//
#include <hip/hip_runtime.h>
#include <hip/hip_bf16.h>

#define N 8192
#define FIN 512
#define FOUT 256

typedef __attribute__((ext_vector_type(8))) short bf16x8;
typedef __attribute__((ext_vector_type(4))) float f32x4;

__device__ __forceinline__ unsigned short f2bf(float x) {
  unsigned int u = __float_as_uint(x);
  return (unsigned short)((u + 0x7FFFu + ((u >> 16) & 1u)) >> 16);
}

// ---------------------------------------------------------------------------
// K1: h = features(8192x512) @ W(512x256), fp32 vector GEMM, 64x64 tile.
// Epilogue also writes hT (bf16, [FOUT][N]) for K4's B-operand staging.
// ---------------------------------------------------------------------------
__global__ __launch_bounds__(256) void gat_k1_gemm_h(
    const float* __restrict__ A, const float* __restrict__ W,
    float* __restrict__ h, unsigned short* __restrict__ hT) {
  __shared__ __align__(16) float As[16][68];
  __shared__ __align__(16) float Bs[16][64];
  const int tid = threadIdx.x;
  const int tx = tid & 15, ty = tid >> 4;
  const int nb = blockIdx.x * 64, mb = blockIdx.y * 64;
  float acc[4][4] = {};
  for (int k0 = 0; k0 < FIN; k0 += 16) {
#pragma unroll
    for (int i = 0; i < 4; ++i) {
      int e = tid + 256 * i;
      int m = e >> 4, k = e & 15;
      As[k][m] = A[(size_t)(mb + m) * FIN + k0 + k];
      int n2 = e & 63, k2 = e >> 6;
      Bs[k2][n2] = W[(size_t)(k0 + k2) * FOUT + nb + n2];
    }
    __syncthreads();
#pragma unroll
    for (int k = 0; k < 16; ++k) {
      float4 av = *reinterpret_cast<const float4*>(&As[k][ty * 4]);
      float4 bv = *reinterpret_cast<const float4*>(&Bs[k][tx * 4]);
      float aa[4] = {av.x, av.y, av.z, av.w};
      float bb[4] = {bv.x, bv.y, bv.z, bv.w};
#pragma unroll
      for (int i = 0; i < 4; ++i)
#pragma unroll
        for (int j = 0; j < 4; ++j) acc[i][j] = fmaf(aa[i], bb[j], acc[i][j]);
    }
    __syncthreads();
  }
#pragma unroll
  for (int i = 0; i < 4; ++i) {
    int m = mb + ty * 4 + i;
#pragma unroll
    for (int j = 0; j < 4; ++j) {
      int n = nb + tx * 4 + j;
      h[(size_t)m * FOUT + n] = acc[i][j];
      hT[(size_t)n * N + m] = f2bf(acc[i][j]);
    }
  }
}

// ---------------------------------------------------------------------------
// K2: hs[i] = h[i,:]@a[:256], hd[i] = h[i,:]@a[256:]. One wave per row.
// Also zero-fills `out` (8 MB) so K4's split-K atomics can accumulate.
// ---------------------------------------------------------------------------
__global__ __launch_bounds__(256) void gat_k2_hshd(
    const float* __restrict__ h, const float* __restrict__ a,
    float* __restrict__ hs, float* __restrict__ hd, float* __restrict__ out) {
  // zero out: 8192*256 floats = 524288 float4 = gridDim(2048)*256 threads
  const int gid = blockIdx.x * 256 + threadIdx.x;
  *reinterpret_cast<float4*>(out + (size_t)gid * 4) =
      make_float4(0.f, 0.f, 0.f, 0.f);

  const int wid = threadIdx.x >> 6;
  const int lane = threadIdx.x & 63;
  const int row = blockIdx.x * 4 + wid;
  float ps = 0.f, pd = 0.f;
#pragma unroll
  for (int i = 0; i < 4; ++i) {
    int c = lane + 64 * i;
    float v = h[(size_t)row * FOUT + c];
    ps += v * a[c];
    pd += v * a[FOUT + c];
  }
#pragma unroll
  for (int off = 32; off >= 1; off >>= 1) {
    ps += __shfl_down(ps, off);
    pd += __shfl_down(pd, off);
  }
  if (lane == 0) {
    hs[row] = ps;
    hd[row] = pd;
  }
}

// ---------------------------------------------------------------------------
// K3: masked softmax rows, float4-vectorized. One streaming pass of adj per
// row; 32 logits/thread in registers. 8 rows/block amortize the hd LDS stage.
// ---------------------------------------------------------------------------
__global__ __launch_bounds__(256) void gat_k3_attn(
    const float* __restrict__ adj, const float* __restrict__ hs,
    const float* __restrict__ hd, float* __restrict__ att) {
  __shared__ __align__(16) float hd_s[N];  // 32 KB
  __shared__ float red[4];
  const int tid = threadIdx.x;
  const int lane = tid & 63, wid = tid >> 6;
#pragma unroll
  for (int i = 0; i < 8; ++i) {
    int j = tid * 4 + 1024 * i;
    *reinterpret_cast<float4*>(&hd_s[j]) =
        *reinterpret_cast<const float4*>(&hd[j]);
  }
  __syncthreads();
  const int row0 = blockIdx.x * 8;
  for (int r = 0; r < 8; ++r) {
    const int row = row0 + r;
    const float hsv = hs[row];
    const float* arow = adj + (size_t)row * N;
    float4 l[8];
    float m = -__builtin_inff();
#pragma unroll
    for (int i = 0; i < 8; ++i) {
      int j = tid * 4 + 1024 * i;
      float4 a4 = *reinterpret_cast<const float4*>(&arow[j]);
      float4 h4 = *reinterpret_cast<const float4*>(&hd_s[j]);
      float4 lv;
      float x;
      x = hsv + h4.x; x = x > 0.f ? x : 0.01f * x;
      lv.x = (a4.x != 0.f) ? x : -__builtin_inff();
      x = hsv + h4.y; x = x > 0.f ? x : 0.01f * x;
      lv.y = (a4.y != 0.f) ? x : -__builtin_inff();
      x = hsv + h4.z; x = x > 0.f ? x : 0.01f * x;
      lv.z = (a4.z != 0.f) ? x : -__builtin_inff();
      x = hsv + h4.w; x = x > 0.f ? x : 0.01f * x;
      lv.w = (a4.w != 0.f) ? x : -__builtin_inff();
      l[i] = lv;
      m = fmaxf(m, fmaxf(fmaxf(lv.x, lv.y), fmaxf(lv.z, lv.w)));
    }
#pragma unroll
    for (int off = 32; off >= 1; off >>= 1) m = fmaxf(m, __shfl_down(m, off));
    if (lane == 0) red[wid] = m;
    __syncthreads();
    m = fmaxf(fmaxf(red[0], red[1]), fmaxf(red[2], red[3]));
    __syncthreads();
    float s = 0.f;
#pragma unroll
    for (int i = 0; i < 8; ++i) {
      float4 lv = l[i];
      lv.x = __expf(lv.x - m);
      lv.y = __expf(lv.y - m);
      lv.z = __expf(lv.z - m);
      lv.w = __expf(lv.w - m);
      l[i] = lv;
      s += lv.x + lv.y + lv.z + lv.w;
    }
#pragma unroll
    for (int off = 32; off >= 1; off >>= 1) s += __shfl_down(s, off);
    if (lane == 0) red[wid] = s;
    __syncthreads();
    s = red[0] + red[1] + red[2] + red[3];
    __syncthreads();
    const float inv = 1.f / s;
    float* orow = att + (size_t)row * N;
#pragma unroll
    for (int i = 0; i < 8; ++i) {
      float4 lv = l[i];
      lv.x *= inv; lv.y *= inv; lv.z *= inv; lv.w *= inv;
      *reinterpret_cast<float4*>(&orow[tid * 4 + 1024 * i]) = lv;
    }
  }
}

// ---------------------------------------------------------------------------
// K4: output = attention @ h via bf16 MFMA 16x16x32, split-K.
// BM=128, BN=256 (full F_out), K-split=4 (K-range 2048/block), BK=64.
// Grid = 64 row-blocks x 4 k-quadrants = 256 blocks; 1024 threads = 16 waves
// (4M x 4N, wave tile 32x64, acc 2x4). hT traffic = 256 blocks x 1 MB panel;
// XCD-aware mapping puts ONE k-quadrant per XCD so its 1 MB hT panel stays
// L2-resident. att read exactly once (268 MB). Partials combined with f32
// atomicAdd into out (zeroed by K2).
// Reg-staged double-buffered 1-barrier pipeline; XOR-swizzled LDS
// (16B-slot bits of row byte offset ^= (row&7)<<4).
// ---------------------------------------------------------------------------
__global__ __launch_bounds__(1024) void gat_k4_out(
    const float* __restrict__ att, const unsigned short* __restrict__ hT,
    float* __restrict__ C) {
  __shared__ __align__(16) unsigned short As[2][128 * 64];  // 2 x 16 KB
  __shared__ __align__(16) unsigned short Bs[2][256 * 64];  // 2 x 32 KB
  const int tid = threadIdx.x;
  const int lane = tid & 63;
  const int wid = tid >> 6;  // 0..15
  const int wm = wid >> 2, wn = wid & 3;
  const int g = lane >> 4, rsel = lane & 15;
  // block mapping: XCD g=id%8 gets k-quadrant g&3 (hT panel L2-resident)
  const int id = blockIdx.x;
  const int grp = id & 7, pos = id >> 3;
  const int kq = grp & 3;
  const int rb = (grp >> 2) + 2 * pos;
  const int row0 = rb * 128;
  const int kbase = kq * 2048;

  // A staging (2 float4/thread): e = tid+1024*i -> row r=e>>4, slot p=e&15
  const float* asrc[2];
  int abyte[2];
#pragma unroll
  for (int i = 0; i < 2; ++i) {
    int e = tid + 1024 * i;
    int r = e >> 4, p = e & 15;
    asrc[i] = att + (size_t)(row0 + r) * N + kbase + p * 4;
    abyte[i] = r * 128 + ((p * 8) ^ ((r & 7) << 4));
  }
  // B staging (2 uint4/thread): s = tid+1024*i -> n=s>>3, kg=s&7, src presw.
  const unsigned short* bsrc[2];
  int bbyte[2];
#pragma unroll
  for (int i = 0; i < 2; ++i) {
    int s = tid + 1024 * i;
    int n = s >> 3, kg = s & 7;
    int kgs = kg ^ (n & 7);
    bsrc[i] = hT + (size_t)n * N + kbase + kgs * 8;
    bbyte[i] = s * 16;
  }

  f32x4 acc[2][4] = {};
  float4 aA0, aA1;
  uint4 bB0, bB1;

  // prologue: load + write tile 0
  aA0 = *reinterpret_cast<const float4*>(asrc[0]);
  aA1 = *reinterpret_cast<const float4*>(asrc[1]);
  bB0 = *reinterpret_cast<const uint4*>(bsrc[0]);
  bB1 = *reinterpret_cast<const uint4*>(bsrc[1]);
  {
    uint2 pk;
    pk.x = (unsigned)f2bf(aA0.x) | ((unsigned)f2bf(aA0.y) << 16);
    pk.y = (unsigned)f2bf(aA0.z) | ((unsigned)f2bf(aA0.w) << 16);
    *reinterpret_cast<uint2*>(reinterpret_cast<char*>(As[0]) + abyte[0]) = pk;
    pk.x = (unsigned)f2bf(aA1.x) | ((unsigned)f2bf(aA1.y) << 16);
    pk.y = (unsigned)f2bf(aA1.z) | ((unsigned)f2bf(aA1.w) << 16);
    *reinterpret_cast<uint2*>(reinterpret_cast<char*>(As[0]) + abyte[1]) = pk;
    *reinterpret_cast<uint4*>(reinterpret_cast<char*>(Bs[0]) + bbyte[0]) = bB0;
    *reinterpret_cast<uint4*>(reinterpret_cast<char*>(Bs[0]) + bbyte[1]) = bB1;
  }

  int cur = 0;
  for (int t = 0; t < 32; ++t) {
    const int knext = (t + 1) * 64;
    if (t < 31) {  // issue next tile's loads early
      aA0 = *reinterpret_cast<const float4*>(asrc[0] + knext);
      aA1 = *reinterpret_cast<const float4*>(asrc[1] + knext);
      bB0 = *reinterpret_cast<const uint4*>(bsrc[0] + knext);
      bB1 = *reinterpret_cast<const uint4*>(bsrc[1] + knext);
    }
    __syncthreads();
    const char* Ac = reinterpret_cast<const char*>(As[cur]);
    const char* Bc = reinterpret_cast<const char*>(Bs[cur]);
#pragma unroll
    for (int ks = 0; ks < 2; ++ks) {
      bf16x8 af[2], bg[4];
#pragma unroll
      for (int f = 0; f < 2; ++f) {
        int r = wm * 32 + f * 16 + rsel;
        af[f] = *reinterpret_cast<const bf16x8*>(
            Ac + r * 128 + ((ks * 64 + g * 16) ^ ((r & 7) << 4)));
      }
#pragma unroll
      for (int f = 0; f < 4; ++f) {
        int n = wn * 64 + f * 16 + rsel;
        bg[f] = *reinterpret_cast<const bf16x8*>(
            Bc + n * 128 + ((ks * 64 + g * 16) ^ ((n & 7) << 4)));
      }
#pragma unroll
      for (int i = 0; i < 2; ++i)
#pragma unroll
        for (int j = 0; j < 4; ++j)
          acc[i][j] = __builtin_amdgcn_mfma_f32_16x16x32_bf16(af[i], bg[j],
                                                              acc[i][j], 0, 0, 0);
    }
    if (t < 31) {
      char* An = reinterpret_cast<char*>(As[cur ^ 1]);
      char* Bn = reinterpret_cast<char*>(Bs[cur ^ 1]);
      uint2 pk;
      pk.x = (unsigned)f2bf(aA0.x) | ((unsigned)f2bf(aA0.y) << 16);
      pk.y = (unsigned)f2bf(aA0.z) | ((unsigned)f2bf(aA0.w) << 16);
      *reinterpret_cast<uint2*>(An + abyte[0]) = pk;
      pk.x = (unsigned)f2bf(aA1.x) | ((unsigned)f2bf(aA1.y) << 16);
      pk.y = (unsigned)f2bf(aA1.z) | ((unsigned)f2bf(aA1.w) << 16);
      *reinterpret_cast<uint2*>(An + abyte[1]) = pk;
      *reinterpret_cast<uint4*>(Bn + bbyte[0]) = bB0;
      *reinterpret_cast<uint4*>(Bn + bbyte[1]) = bB1;
      cur ^= 1;
    }
  }
  // epilogue: split-K accumulate. C/D layout col=lane&15, row=(lane>>4)*4+reg
#pragma unroll
  for (int i = 0; i < 2; ++i)
#pragma unroll
    for (int j = 0; j < 4; ++j)
#pragma unroll
      for (int r = 0; r < 4; ++r) {
        int row = row0 + wm * 32 + i * 16 + g * 4 + r;
        int col = wn * 64 + j * 16 + rsel;
        atomicAdd(&C[(size_t)row * FOUT + col], acc[i][j][r]);
      }
}

extern "C" void kernel_launch(void* const* d_in, const int* in_sizes, int n_in,
                              void* d_out, int out_size, void* d_ws, size_t ws_size,
                              hipStream_t stream) {
  const float* features = (const float*)d_in[0];
  const float* adj = (const float*)d_in[1];
  const float* W = (const float*)d_in[2];
  const float* a = (const float*)d_in[3];

  float* out = (float*)d_out;           // [N][FOUT]
  float* att = out + (size_t)N * FOUT;  // [N][N]

  char* ws = (char*)d_ws;
  float* h = (float*)ws;                                              // 8 MB
  unsigned short* hT = (unsigned short*)(ws + (size_t)N * FOUT * 4);  // 4 MB
  float* hs = (float*)(ws + (size_t)N * FOUT * 4 + (size_t)N * FOUT * 2);
  float* hd = hs + N;

  hipLaunchKernelGGL(gat_k1_gemm_h, dim3(FOUT / 64, N / 64), dim3(256), 0,
                     stream, features, W, h, hT);
  hipLaunchKernelGGL(gat_k2_hshd, dim3(N / 4), dim3(256), 0, stream, h, a, hs,
                     hd, out);
  hipLaunchKernelGGL(gat_k3_attn, dim3(N / 8), dim3(256), 0, stream, adj, hs,
                     hd, att);
  hipLaunchKernelGGL(gat_k4_out, dim3(256), dim3(1024), 0, stream, att, hT,
                     out);
}